// Round 18
// baseline (85.817 us; speedup 1.0000x reference)
//
#include <hip/hip_runtime.h>
#include <hip/hip_bf16.h>

typedef __bf16 bf16_t;
typedef __attribute__((ext_vector_type(8))) __bf16 bf16x8;
typedef __attribute__((ext_vector_type(4))) float f32x4;

#define KDIM 1152
#define NDIM 1152
#define BM 128
#define BN 288
#define BK 32
#define NIT 36                        /* K-steps of 32 */
#define NTILES 4                      /* 1152/288 */
#define A_STEP 8192                   /* BM*BK*2 bytes per (panel,ktile) */
#define A_PANEL 294912                /* BM*KDIM*2 bytes per m-panel */
#define B_STEP 18432                  /* BN*BK*2 bytes per ktile */
#define B_TILE (36 * B_STEP)          /* 663552 B per n-tile panel */
#define CVT_BLOCKS 4608               /* 2 rb-groups per wave */

__device__ __forceinline__ void gload_lds16(const void* g, void* l) {
    __builtin_amdgcn_global_load_lds(
        (const __attribute__((address_space(1))) void*)g,
        (__attribute__((address_space(3))) void*)l, 16, 0, 0);
}

// Fused prep: blocks [0,4608) cvt X fp32->bf16 frag-order, 2 rb-groups/wave
// (2x ILP, 2KB contiguous global write per wave); blocks [4608,5184) fold
// W -> Weff (BN=288 layout) + bias.
// Xb: unit = P*18432 + T*512 + rb*64 + g*16 + r0 -> row P*128+rb*16+r0, k=T*32+g*8.
// Weff: idx(n,k) = tile*331776 + (k>>5)*9216 + (nin>>4)*512 + ((k>>3)&3)*128
//       + (nin&15)*8 + (k&7)   (tile = n/288, nin = n%288)
__global__ void prep(const float* __restrict__ X, bf16_t* __restrict__ Xb,
                     const float* __restrict__ W, const float* __restrict__ bvec,
                     bf16_t* __restrict__ Bm, float* __restrict__ bias)
{
    __shared__ char L[8192];
    const int bid = blockIdx.x;
    const int tid = threadIdx.x;
    if (bid < CVT_BLOCKS) {
        const int gv = (bid << 3) + ((tid >> 6) << 1);   // first group id (even)
        const int l = tid & 63;
        char* wl = L + (tid >> 6) * 2048;
        // group 0
        {
            const int P = gv / 288;
            const int rem = gv - P * 288;
            const int T = rem >> 3;
            const int rb = rem & 7;
            const int row = P * 128 + rb * 16 + (l >> 2);
            const int k = T * 32 + (l & 3) * 8;
            const float* src = X + (size_t)row * KDIM + k;
            f32x4 lo = *(const f32x4*)src;
            f32x4 hi = *(const f32x4*)(src + 4);
            bf16x8 v;
            #pragma unroll
            for (int e = 0; e < 4; ++e) { v[e] = (__bf16)lo[e]; v[4 + e] = (__bf16)hi[e]; }
            *(bf16x8*)(wl + ((l & 3) * 16 + (l >> 2)) * 16) = v;
        }
        // group 1 (gv+1: same T unless rb wraps — recompute exactly)
        {
            const int g1 = gv + 1;
            const int P = g1 / 288;
            const int rem = g1 - P * 288;
            const int T = rem >> 3;
            const int rb = rem & 7;
            const int row = P * 128 + rb * 16 + (l >> 2);
            const int k = T * 32 + (l & 3) * 8;
            const float* src = X + (size_t)row * KDIM + k;
            f32x4 lo = *(const f32x4*)src;
            f32x4 hi = *(const f32x4*)(src + 4);
            bf16x8 v;
            #pragma unroll
            for (int e = 0; e < 4; ++e) { v[e] = (__bf16)lo[e]; v[4 + e] = (__bf16)hi[e]; }
            *(bf16x8*)(wl + 1024 + ((l & 3) * 16 + (l >> 2)) * 16) = v;
        }
        __builtin_amdgcn_s_barrier();
        bf16x8 o0 = *(const bf16x8*)(wl + l * 16);
        bf16x8 o1 = *(const bf16x8*)(wl + 1024 + l * 16);
        char* dst = (char*)Xb + (size_t)gv * 1024;       // 2KB contiguous per wave
        *(bf16x8*)(dst + l * 16) = o0;
        *(bf16x8*)(dst + 1024 + l * 16) = o1;
        return;
    }
    const int t = (bid - CVT_BLOCKS) * 256 + tid;
    if (t < NDIM) {
        const int o = t / 9, p = t - o * 9;
        bias[t] = bvec[p * 128 + o];
    }
    const int c = t & 127;
    const int o = (t >> 7) & 127;
    const int p = t >> 14;
    if (p >= 9) return;
    const int r = p / 3, cc = p - r * 3;
    float eff[3][3] = {{0.f,0.f,0.f},{0.f,0.f,0.f},{0.f,0.f,0.f}};
    const float* w = W + (size_t)((p * 128 + o) * 128 + c) * 9;
    #pragma unroll
    for (int i = 0; i < 3; ++i) {
        const int a = (2 + r + i) / 3;
        #pragma unroll
        for (int j = 0; j < 3; ++j) {
            const int bb = (2 + cc + j) / 3;
            eff[a][bb] += w[i * 3 + j];
        }
    }
    const int n = o * 9 + p;
    const int tile = n / BN;
    const int nin = n - tile * BN;
    #pragma unroll
    for (int a = 0; a < 3; ++a)
        #pragma unroll
        for (int bb = 0; bb < 3; ++bb) {
            const int k = c * 9 + a * 3 + bb;
            const size_t idx = (size_t)tile * (B_TILE / 2)
                             + (k >> 5) * (B_STEP / 2)
                             + (nin >> 4) * 512 + ((k >> 3) & 3) * 128
                             + (nin & 15) * 8 + (k & 7);
            Bm[idx] = (bf16_t)eff[a][bb];
        }
}

// out[16384,1152] = Xb(bf16 frag-order) * Weff(bf16) + bias.
// r17 geometry + RING-3 single-barrier K-loop:
// BM=128 x BN=288, grid 512 = 2 blocks/CU, 4 waves (2m x 2n), wave 64x144.
// LDS: A 3x8K + B 3x18K + scrap = 79KB (x2 blocks = 158KB).
// Per iter: GLD(t+2 -> slot (t+2)%3, safe: last read at t-1, barrier passed)
//   -> 13 ds_read slot t -> lgkm0 -> 36 MFMA -> vmcnt(7) -> ONE barrier.
// 36 barriers total (was 72); staging issue overlaps ds_read latency;
// vmcnt never 0 until the tail.
__launch_bounds__(256, 2)
__global__ void ind_gemm(const bf16_t* __restrict__ Xb,
                         const bf16_t* __restrict__ Bm,
                         const float* __restrict__ bias,
                         float* __restrict__ out)
{
    __shared__ char As[3][A_STEP];
    __shared__ char Bs[3][B_STEP];
    __shared__ char Scrap[1024];

    const int tid = threadIdx.x;
    const int lane = tid & 63;
    const int wid = tid >> 6;
    const int wm = wid >> 1;        // 0..1
    const int wn = wid & 1;         // 0..1

    // XCD swizzle: 512 blocks = 64/XCD; consecutive swz share an m-panel
    // (147KB bf16, L2-resident) across the 4 n-tiles.
    const int bid = blockIdx.x;
    const int swz = (bid & 7) * 64 + (bid >> 3);
    const int mt = swz >> 2;
    const int nt = swz & 3;
    const int m0 = mt * BM;

    const int fr = (lane >> 4) * 256 + (lane & 15) * 16;
    const char* apanel = (const char*)Xb + (size_t)mt * A_PANEL;
    const char* bpanel = (const char*)Bm + (size_t)nt * B_TILE;

    f32x4 acc[4][9];
    #pragma unroll
    for (int i = 0; i < 4; ++i)
        #pragma unroll
        for (int j = 0; j < 9; ++j)
            acc[i][j] = (f32x4){0.f, 0.f, 0.f, 0.f};

    bf16x8 af[4], bfr[9];

    #define GLD(T, SLOT) do {                                               \
        const char* sa_ = apanel + (size_t)(T) * A_STEP;                    \
        gload_lds16(sa_ + tid * 16,        &As[SLOT][tid * 16]);            \
        gload_lds16(sa_ + 4096 + tid * 16, &As[SLOT][4096 + tid * 16]);     \
        const char* sb_ = bpanel + (size_t)(T) * B_STEP;                    \
        _Pragma("unroll")                                                   \
        for (int r_ = 0; r_ < 4; ++r_) {                                    \
            const int u_ = (tid + r_ * 256) * 16;                           \
            gload_lds16(sb_ + u_, &Bs[SLOT][u_]);                           \
        }                                                                   \
        if (tid < 128) gload_lds16(sb_ + (1024 + tid) * 16,                 \
                                   &Bs[SLOT][(1024 + tid) * 16]);           \
        else           gload_lds16(bpanel + tid * 16, Scrap);               \
    } while (0)

    #define RD(SLOT) do {                                                   \
        _Pragma("unroll")                                                   \
        for (int mi_ = 0; mi_ < 4; ++mi_)                                   \
            af[mi_] = *(const bf16x8*)(&As[SLOT][(wm * 4 + mi_) * 1024 + fr]); \
        _Pragma("unroll")                                                   \
        for (int j_ = 0; j_ < 9; ++j_)                                      \
            bfr[j_] = *(const bf16x8*)(&Bs[SLOT][(wn * 9 + j_) * 1024 + fr]); \
        asm volatile("s_waitcnt lgkmcnt(0)" ::: "memory");                  \
        __builtin_amdgcn_sched_barrier(0);                                  \
    } while (0)

    #define MFMA36() do {                                                   \
        __builtin_amdgcn_s_setprio(1);                                      \
        _Pragma("unroll")                                                   \
        for (int mi_ = 0; mi_ < 4; ++mi_)                                   \
            _Pragma("unroll")                                               \
            for (int j_ = 0; j_ < 9; ++j_)                                  \
                acc[mi_][j_] = __builtin_amdgcn_mfma_f32_16x16x32_bf16(     \
                    af[mi_], bfr[j_], acc[mi_][j_], 0, 0, 0);               \
        __builtin_amdgcn_s_setprio(0);                                      \
    } while (0)

    #define WAITV(N) do {                                                   \
        asm volatile("s_waitcnt vmcnt(" #N ")" ::: "memory");               \
        __builtin_amdgcn_sched_barrier(0);                                  \
    } while (0)

    #define ITER(T, SLOT, SLOT2) do {                                       \
        GLD((T) + 2, SLOT2);   /* into slot read at T-1 (barrier-safe) */   \
        RD(SLOT);                                                           \
        MFMA36();                                                           \
        WAITV(7);              /* drains t+1; t+2 stays in flight */        \
        __builtin_amdgcn_s_barrier();                                       \
    } while (0)

    // ---- prologue: t0[7] + t1[7] in flight; drain t0, keep t1 flying ----
    GLD(0, 0);
    GLD(1, 1);
    WAITV(7);
    __builtin_amdgcn_s_barrier();

    // steady state: t = 0..32 (11 x 3, static slot indices)
    #pragma unroll 1
    for (int tt = 0; tt < 11; ++tt) {
        const int t = 3 * tt;
        ITER(t,     0, 2);
        ITER(t + 1, 1, 0);
        ITER(t + 2, 2, 1);
    }
    // t = 33 (slot 0): stage t=35 into slot 2
    ITER(33, 0, 2);
    // t = 34 (slot 1): nothing left to stage; drain all
    RD(1);
    MFMA36();
    WAITV(0);
    __builtin_amdgcn_s_barrier();
    // t = 35 (slot 2): compute-only
    RD(2);
    MFMA36();

    #undef GLD
    #undef RD
    #undef MFMA36
    #undef WAITV
    #undef ITER

    // ---- epilogue: C/D col=lane&15, row=(lane>>4)*4+reg ----
    const int orow = (lane >> 4) * 4;
    const int ocol = lane & 15;
    const int gn0 = nt * BN + wn * 144 + ocol;
    #pragma unroll
    for (int ni = 0; ni < 9; ++ni) {
        const float bv = bias[gn0 + ni * 16];
        #pragma unroll
        for (int mi = 0; mi < 4; ++mi) {
            float* po = out + (size_t)(m0 + wm * 64 + mi * 16 + orow) * NDIM
                            + gn0 + ni * 16;
            #pragma unroll
            for (int r = 0; r < 4; ++r)
                po[(size_t)r * NDIM] = acc[mi][ni][r] + bv;
        }
    }
}

extern "C" void kernel_launch(void* const* d_in, const int* in_sizes, int n_in,
                              void* d_out, int out_size, void* d_ws, size_t ws_size,
                              hipStream_t stream)
{
    const float* x  = (const float*)d_in[0];
    const float* W  = (const float*)d_in[1];
    const float* bv = (const float*)d_in[2];
    float* out = (float*)d_out;

    // ws: Xb 37.75 MB | Bm 2.65 MB | bias 4.6 KB
    bf16_t* Xb   = (bf16_t*)d_ws;
    bf16_t* Bm   = (bf16_t*)((char*)d_ws + (size_t)16384 * KDIM * sizeof(bf16_t));
    float*  bias = (float*)((char*)Bm + (size_t)KDIM * NDIM * sizeof(bf16_t));

    prep<<<CVT_BLOCKS + 576, 256, 0, stream>>>(x, Xb, W, bv, Bm, bias);
    ind_gemm<<<512, 256, 0, stream>>>(Xb, Bm, bias, out);
}

// Round 19
// 78.475 us; speedup vs baseline: 1.0936x; 1.0936x over previous
//
#include <hip/hip_runtime.h>
#include <hip/hip_bf16.h>

typedef __bf16 bf16_t;
typedef __attribute__((ext_vector_type(8))) __bf16 bf16x8;
typedef __attribute__((ext_vector_type(4))) float f32x4;

#define KDIM 1152
#define NDIM 1152
#define BM 128
#define BN 288
#define BK 32
#define NIT 36                        /* K-steps of 32 */
#define NTILES 4                      /* 1152/288 */
#define A_STEP 8192                   /* BM*BK*2 bytes per (panel,ktile) */
#define A_PANEL 294912                /* BM*KDIM*2 bytes per m-panel */
#define B_STEP 18432                  /* BN*BK*2 bytes per ktile */
#define B_TILE (36 * B_STEP)          /* 663552 B per n-tile panel */
#define CVT_BLOCKS 2304               /* 4 waves x 4 rb-groups per block */

__device__ __forceinline__ void gload_lds16(const void* g, void* l) {
    __builtin_amdgcn_global_load_lds(
        (const __attribute__((address_space(1))) void*)g,
        (__attribute__((address_space(3))) void*)l, 16, 0, 0);
}

// Fused prep: blocks [0,2304) cvt X fp32->bf16 frag-order, 4 rb-groups/wave
// (8 independent 32B loads/lane for ILP; wave-local LDS transpose with NO
// block barrier — lgkmcnt(0) fence only; 4KB contiguous global write/wave);
// blocks [2304,2880) fold W -> Weff (BN=288 layout) + bias.
// Xb: unit = P*18432 + T*512 + rb*64 + g*16 + r0 -> row P*128+rb*16+r0, k=T*32+g*8.
// Weff: idx(n,k) = tile*331776 + (k>>5)*9216 + (nin>>4)*512 + ((k>>3)&3)*128
//       + (nin&15)*8 + (k&7)   (tile = n/288, nin = n%288)
__global__ void prep(const float* __restrict__ X, bf16_t* __restrict__ Xb,
                     const float* __restrict__ W, const float* __restrict__ bvec,
                     bf16_t* __restrict__ Bm, float* __restrict__ bias)
{
    __shared__ char L[16384];
    const int bid = blockIdx.x;
    const int tid = threadIdx.x;
    if (bid < CVT_BLOCKS) {
        const int gv0 = (bid << 4) + ((tid >> 6) << 2);  // first of 4 group ids
        const int l = tid & 63;
        char* wl = L + (tid >> 6) * 4096;
        #pragma unroll
        for (int i = 0; i < 4; ++i) {
            const int g = gv0 + i;
            const int P = g / 288;
            const int rem = g - P * 288;
            const int T = rem >> 3;
            const int rb = rem & 7;
            const int row = P * 128 + rb * 16 + (l >> 2);
            const int k = T * 32 + (l & 3) * 8;
            const float* src = X + (size_t)row * KDIM + k;
            f32x4 lo = *(const f32x4*)src;
            f32x4 hi = *(const f32x4*)(src + 4);
            bf16x8 v;
            #pragma unroll
            for (int e = 0; e < 4; ++e) { v[e] = (__bf16)lo[e]; v[4 + e] = (__bf16)hi[e]; }
            *(bf16x8*)(wl + i * 1024 + ((l & 3) * 16 + (l >> 2)) * 16) = v;
        }
        // wave-local round trip: only this wave reads its slice -> lgkm fence
        asm volatile("s_waitcnt lgkmcnt(0)" ::: "memory");
        __builtin_amdgcn_sched_barrier(0);
        char* dst = (char*)Xb + (size_t)gv0 * 1024;      // 4KB contiguous per wave
        #pragma unroll
        for (int i = 0; i < 4; ++i) {
            bf16x8 o = *(const bf16x8*)(wl + i * 1024 + l * 16);
            *(bf16x8*)(dst + i * 1024 + l * 16) = o;
        }
        return;
    }
    const int t = (bid - CVT_BLOCKS) * 256 + tid;
    if (t < NDIM) {
        const int o = t / 9, p = t - o * 9;
        bias[t] = bvec[p * 128 + o];
    }
    const int c = t & 127;
    const int o = (t >> 7) & 127;
    const int p = t >> 14;
    if (p >= 9) return;
    const int r = p / 3, cc = p - r * 3;
    float eff[3][3] = {{0.f,0.f,0.f},{0.f,0.f,0.f},{0.f,0.f,0.f}};
    const float* w = W + (size_t)((p * 128 + o) * 128 + c) * 9;
    #pragma unroll
    for (int i = 0; i < 3; ++i) {
        const int a = (2 + r + i) / 3;
        #pragma unroll
        for (int j = 0; j < 3; ++j) {
            const int bb = (2 + cc + j) / 3;
            eff[a][bb] += w[i * 3 + j];
        }
    }
    const int n = o * 9 + p;
    const int tile = n / BN;
    const int nin = n - tile * BN;
    #pragma unroll
    for (int a = 0; a < 3; ++a)
        #pragma unroll
        for (int bb = 0; bb < 3; ++bb) {
            const int k = c * 9 + a * 3 + bb;
            const size_t idx = (size_t)tile * (B_TILE / 2)
                             + (k >> 5) * (B_STEP / 2)
                             + (nin >> 4) * 512 + ((k >> 3) & 3) * 128
                             + (nin & 15) * 8 + (k & 7);
            Bm[idx] = (bf16_t)eff[a][bb];
        }
}

// out[16384,1152] = Xb(bf16 frag-order) * Weff(bf16) + bias.
// CHAMPION GEMM (round-17 bench: 47.4us, MfmaUtil 36): BM=128 x BN=288,
// grid 512 = exactly 2 blocks/CU, 4 waves (2m x 2n), wave 64x144,
// acc 4x9 = 144 VGPR. Both operands dbuf-LDS via linear gload_lds
// (A 2/thr + B 5/thr, 5th dummy for tid>=128 -> vmcnt uniform).
// Ledger: enter with 7 in flight; stage t+2 (+7); vmcnt(7) drains t+1;
// 0 only at the tail. ds_read-first / stage-during-MFMA order (proven;
// GLD-first ring-3 variant regressed — r18).
__launch_bounds__(256, 2)
__global__ void ind_gemm(const bf16_t* __restrict__ Xb,
                         const bf16_t* __restrict__ Bm,
                         const float* __restrict__ bias,
                         float* __restrict__ out)
{
    __shared__ char As[2][A_STEP];
    __shared__ char Bs[2][B_STEP];
    __shared__ char Scrap[1024];

    const int tid = threadIdx.x;
    const int lane = tid & 63;
    const int wid = tid >> 6;
    const int wm = wid >> 1;        // 0..1
    const int wn = wid & 1;         // 0..1

    // XCD swizzle: 512 blocks = 64/XCD; consecutive swz share an m-panel
    // (147KB bf16, L2-resident) across the 4 n-tiles.
    const int bid = blockIdx.x;
    const int swz = (bid & 7) * 64 + (bid >> 3);
    const int mt = swz >> 2;
    const int nt = swz & 3;
    const int m0 = mt * BM;

    const int fr = (lane >> 4) * 256 + (lane & 15) * 16;
    const char* apanel = (const char*)Xb + (size_t)mt * A_PANEL;
    const char* bpanel = (const char*)Bm + (size_t)nt * B_TILE;

    f32x4 acc[4][9];
    #pragma unroll
    for (int i = 0; i < 4; ++i)
        #pragma unroll
        for (int j = 0; j < 9; ++j)
            acc[i][j] = (f32x4){0.f, 0.f, 0.f, 0.f};

    bf16x8 af[4], bfr[9];

    #define GLD(T, BUF) do {                                                \
        const char* sa_ = apanel + (size_t)(T) * A_STEP;                    \
        gload_lds16(sa_ + tid * 16,        &As[BUF][tid * 16]);             \
        gload_lds16(sa_ + 4096 + tid * 16, &As[BUF][4096 + tid * 16]);      \
        const char* sb_ = bpanel + (size_t)(T) * B_STEP;                    \
        _Pragma("unroll")                                                   \
        for (int r_ = 0; r_ < 4; ++r_) {                                    \
            const int u_ = (tid + r_ * 256) * 16;                           \
            gload_lds16(sb_ + u_, &Bs[BUF][u_]);                            \
        }                                                                   \
        if (tid < 128) gload_lds16(sb_ + (1024 + tid) * 16,                 \
                                   &Bs[BUF][(1024 + tid) * 16]);            \
        else           gload_lds16(bpanel + tid * 16, Scrap);               \
    } while (0)

    #define RD(CUR) do {                                                    \
        _Pragma("unroll")                                                   \
        for (int mi_ = 0; mi_ < 4; ++mi_)                                   \
            af[mi_] = *(const bf16x8*)(&As[CUR][(wm * 4 + mi_) * 1024 + fr]); \
        _Pragma("unroll")                                                   \
        for (int j_ = 0; j_ < 9; ++j_)                                      \
            bfr[j_] = *(const bf16x8*)(&Bs[CUR][(wn * 9 + j_) * 1024 + fr]); \
        asm volatile("s_waitcnt lgkmcnt(0)" ::: "memory");                  \
        __builtin_amdgcn_sched_barrier(0);                                  \
        __builtin_amdgcn_s_barrier();                                       \
    } while (0)

    #define MFMA36() do {                                                   \
        __builtin_amdgcn_s_setprio(1);                                      \
        _Pragma("unroll")                                                   \
        for (int mi_ = 0; mi_ < 4; ++mi_)                                   \
            _Pragma("unroll")                                               \
            for (int j_ = 0; j_ < 9; ++j_)                                  \
                acc[mi_][j_] = __builtin_amdgcn_mfma_f32_16x16x32_bf16(     \
                    af[mi_], bfr[j_], acc[mi_][j_], 0, 0, 0);               \
        __builtin_amdgcn_s_setprio(0);                                      \
    } while (0)

    #define WAITV(N) do {                                                   \
        asm volatile("s_waitcnt vmcnt(" #N ")" ::: "memory");               \
        __builtin_amdgcn_sched_barrier(0);                                  \
    } while (0)

    // ---- prologue: t0[7] + t1[7] in flight; drain t0, keep t1 flying ----
    GLD(0, 0);
    GLD(1, 1);
    WAITV(7);
    __builtin_amdgcn_s_barrier();

    // steady state: 17 double-iters (t = 0..33)
    #pragma unroll 1
    for (int t2 = 0; t2 < 17; ++t2) {
        const int t = 2 * t2;
        // ---- even iter t (cur=0) ----
        RD(0);                       // 13 ds_read, lgkm0, barrier (frees buf0)
        GLD(t + 2, 0);               // +7 -> 14 in flight
        MFMA36();
        WAITV(7);                    // drains t+1; t+2 stays in flight
        __builtin_amdgcn_s_barrier();
        // ---- odd iter t+1 (cur=1) ----
        RD(1);
        GLD(t + 3, 1);
        MFMA36();
        WAITV(7);
        __builtin_amdgcn_s_barrier();
    }
    // ---- t = 34 (cur=0): no staging; drain all ----
    RD(0);
    MFMA36();
    WAITV(0);
    __builtin_amdgcn_s_barrier();
    // ---- t = 35 (cur=1): compute-only ----
    RD(1);
    MFMA36();

    #undef GLD
    #undef RD
    #undef MFMA36
    #undef WAITV

    // ---- epilogue: C/D col=lane&15, row=(lane>>4)*4+reg ----
    const int orow = (lane >> 4) * 4;
    const int ocol = lane & 15;
    const int gn0 = nt * BN + wn * 144 + ocol;
    #pragma unroll
    for (int ni = 0; ni < 9; ++ni) {
        const float bv = bias[gn0 + ni * 16];
        #pragma unroll
        for (int mi = 0; mi < 4; ++mi) {
            float* po = out + (size_t)(m0 + wm * 64 + mi * 16 + orow) * NDIM
                            + gn0 + ni * 16;
            #pragma unroll
            for (int r = 0; r < 4; ++r)
                po[(size_t)r * NDIM] = acc[mi][ni][r] + bv;
        }
    }
}

extern "C" void kernel_launch(void* const* d_in, const int* in_sizes, int n_in,
                              void* d_out, int out_size, void* d_ws, size_t ws_size,
                              hipStream_t stream)
{
    const float* x  = (const float*)d_in[0];
    const float* W  = (const float*)d_in[1];
    const float* bv = (const float*)d_in[2];
    float* out = (float*)d_out;

    // ws: Xb 37.75 MB | Bm 2.65 MB | bias 4.6 KB
    bf16_t* Xb   = (bf16_t*)d_ws;
    bf16_t* Bm   = (bf16_t*)((char*)d_ws + (size_t)16384 * KDIM * sizeof(bf16_t));
    float*  bias = (float*)((char*)Bm + (size_t)KDIM * NDIM * sizeof(bf16_t));

    prep<<<CVT_BLOCKS + 576, 256, 0, stream>>>(x, Xb, W, bv, Bm, bias);
    ind_gemm<<<512, 256, 0, stream>>>(Xb, Bm, bias, out);
}

// Round 20
// 74.445 us; speedup vs baseline: 1.1528x; 1.0541x over previous
//
#include <hip/hip_runtime.h>
#include <hip/hip_bf16.h>

typedef __bf16 bf16_t;
typedef __attribute__((ext_vector_type(8))) __bf16 bf16x8;
typedef __attribute__((ext_vector_type(4))) float f32x4;

#define KDIM 1152
#define NDIM 1152
#define BM 128
#define BN 288
#define BK 32
#define NIT 36                        /* K-steps of 32 */
#define NTILES 4                      /* 1152/288 */
#define AF_STEP 16384                 /* BM*BK*4 bytes (fp32 A tile) */
#define B_STEP 18432                  /* BN*BK*2 bytes per ktile */
#define B_TILE (36 * B_STEP)          /* 663552 B per n-tile panel */

__device__ __forceinline__ void gload_lds16(const void* g, void* l) {
    __builtin_amdgcn_global_load_lds(
        (const __attribute__((address_space(1))) void*)g,
        (__attribute__((address_space(3))) void*)l, 16, 0, 0);
}

// W-fold only (cvt pre-pass deleted — GEMM reads X directly).
// Weff: idx(n,k) = tile*331776 + (k>>5)*9216 + (nin>>4)*512 + ((k>>3)&3)*128
//       + (nin&15)*8 + (k&7)   (tile = n/288, nin = n%288)
__global__ void build_wb(const float* __restrict__ W,
                         const float* __restrict__ bvec,
                         bf16_t* __restrict__ Bm,
                         float* __restrict__ bias)
{
    const int t = blockIdx.x * blockDim.x + threadIdx.x;
    if (t < NDIM) {
        const int o = t / 9, p = t - o * 9;
        bias[t] = bvec[p * 128 + o];
    }
    const int c = t & 127;
    const int o = (t >> 7) & 127;
    const int p = t >> 14;
    if (p >= 9) return;
    const int r = p / 3, cc = p - r * 3;
    float eff[3][3] = {{0.f,0.f,0.f},{0.f,0.f,0.f},{0.f,0.f,0.f}};
    const float* w = W + (size_t)((p * 128 + o) * 128 + c) * 9;
    #pragma unroll
    for (int i = 0; i < 3; ++i) {
        const int a = (2 + r + i) / 3;
        #pragma unroll
        for (int j = 0; j < 3; ++j) {
            const int bb = (2 + cc + j) / 3;
            eff[a][bb] += w[i * 3 + j];
        }
    }
    const int n = o * 9 + p;
    const int tile = n / BN;
    const int nin = n - tile * BN;
    #pragma unroll
    for (int a = 0; a < 3; ++a)
        #pragma unroll
        for (int bb = 0; bb < 3; ++bb) {
            const int k = c * 9 + a * 3 + bb;
            const size_t idx = (size_t)tile * (B_TILE / 2)
                             + (k >> 5) * (B_STEP / 2)
                             + (nin >> 4) * 512 + ((k >> 3) & 3) * 128
                             + (nin & 15) * 8 + (k & 7);
            Bm[idx] = (bf16_t)eff[a][bb];
        }
}

// out[16384,1152] = X(fp32, staged+cvt in-GEMM) * Weff(bf16) + bias.
// Champion sync skeleton (r17/r19): BM=128 x BN=288, grid 512 = 2 blocks/CU,
// 4 waves (2m x 2n), wave 64x144, acc 4x9.
// A: fp32 staged DIRECTLY from X via 4 linear gload_lds/thread into a
//    [row][chunk] tile with XOR-swizzle applied on the GLOBAL SOURCE side
//    (rule 21: linear LDS dest, kb = kbx ^ (row&7); read applies same XOR
//    -> 2-way max bank aliasing = free). cvt fp32->bf16 in-register,
//    fused per-mi into the MFMA cluster.
// B: bf16 frag-order panel, 5 gload_lds/thread (5th dummy for tid>=128).
// Ledger: GLD = 9 uniform; enter 9 in flight; stage t+2 (+9); vmcnt(9)
// drains t+1; 0 only at the tail.
__launch_bounds__(256, 2)
__global__ void ind_gemm(const float* __restrict__ X,
                         const bf16_t* __restrict__ Bm,
                         const float* __restrict__ bias,
                         float* __restrict__ out)
{
    __shared__ char Af[2][AF_STEP];
    __shared__ char Bs[2][B_STEP];
    __shared__ char Scrap[1024];

    const int tid = threadIdx.x;
    const int lane = tid & 63;
    const int wid = tid >> 6;
    const int wm = wid >> 1;        // 0..1
    const int wn = wid & 1;         // 0..1

    // XCD swizzle: 512 blocks = 64/XCD; consecutive swz share an m-panel
    // (X panel 590KB fp32, L2-resident) across the 4 n-tiles.
    const int bid = blockIdx.x;
    const int swz = (bid & 7) * 64 + (bid >> 3);
    const int mt = swz >> 2;
    const int nt = swz & 3;
    const int m0 = mt * BM;

    // ---- A staging addressing ----
    // unit v = tid + r*256: row = (tid>>3)+32r, LDS slot kbx = tid&7.
    // source chunk kb = kbx ^ (row&7) = (tid&7) ^ ((tid>>3)&7)  (32r = 0 mod 8)
    const int row0 = tid >> 3;
    const int kb0 = (tid & 7) ^ (row0 & 7);
    const char* asrc = (const char*)(X + (size_t)(m0 + row0) * KDIM + kb0 * 4);
    // per iter T: +T*128 B; per r: +r*147456 B (32 rows)

    // ---- A frag read offsets (XOR on read side) ----
    const int abase = (wm * 64 + (lane & 15)) * 128;  // + mi*2048
    const int g2 = (lane >> 4) * 2;
    const int x0 = ((g2)     ^ (lane & 7)) * 16;
    const int x1 = ((g2 + 1) ^ (lane & 7)) * 16;

    const int fr = (lane >> 4) * 256 + (lane & 15) * 16;
    const char* bpanel = (const char*)Bm + (size_t)nt * B_TILE;

    f32x4 acc[4][9];
    #pragma unroll
    for (int i = 0; i < 4; ++i)
        #pragma unroll
        for (int j = 0; j < 9; ++j)
            acc[i][j] = (f32x4){0.f, 0.f, 0.f, 0.f};

    f32x4 alo[4], ahi[4];
    bf16x8 bfr[9];

    #define GLD(T, BUF) do {                                                \
        const char* sa_ = asrc + (size_t)(T) * 128;                         \
        _Pragma("unroll")                                                   \
        for (int r_ = 0; r_ < 4; ++r_)                                      \
            gload_lds16(sa_ + (size_t)r_ * 147456,                          \
                        &Af[BUF][tid * 16 + r_ * 4096]);                    \
        const char* sb_ = bpanel + (size_t)(T) * B_STEP;                    \
        _Pragma("unroll")                                                   \
        for (int r_ = 0; r_ < 4; ++r_) {                                    \
            const int u_ = (tid + r_ * 256) * 16;                           \
            gload_lds16(sb_ + u_, &Bs[BUF][u_]);                            \
        }                                                                   \
        if (tid < 128) gload_lds16(sb_ + (1024 + tid) * 16,                 \
                                   &Bs[BUF][(1024 + tid) * 16]);            \
        else           gload_lds16(bpanel + tid * 16, Scrap);               \
    } while (0)

    #define RD(CUR) do {                                                    \
        _Pragma("unroll")                                                   \
        for (int mi_ = 0; mi_ < 4; ++mi_) {                                 \
            alo[mi_] = *(const f32x4*)(&Af[CUR][abase + mi_ * 2048 + x0]);  \
            ahi[mi_] = *(const f32x4*)(&Af[CUR][abase + mi_ * 2048 + x1]);  \
        }                                                                   \
        _Pragma("unroll")                                                   \
        for (int j_ = 0; j_ < 9; ++j_)                                      \
            bfr[j_] = *(const bf16x8*)(&Bs[CUR][(wn * 9 + j_) * 1024 + fr]); \
        asm volatile("s_waitcnt lgkmcnt(0)" ::: "memory");                  \
        __builtin_amdgcn_sched_barrier(0);                                  \
        __builtin_amdgcn_s_barrier();                                       \
    } while (0)

    #define MFMA36() do {                                                   \
        __builtin_amdgcn_s_setprio(1);                                      \
        _Pragma("unroll")                                                   \
        for (int mi_ = 0; mi_ < 4; ++mi_) {                                 \
            bf16x8 a_;                                                      \
            _Pragma("unroll")                                               \
            for (int e_ = 0; e_ < 4; ++e_) {                                \
                a_[e_]     = (__bf16)alo[mi_][e_];                          \
                a_[4 + e_] = (__bf16)ahi[mi_][e_];                          \
            }                                                               \
            _Pragma("unroll")                                               \
            for (int j_ = 0; j_ < 9; ++j_)                                  \
                acc[mi_][j_] = __builtin_amdgcn_mfma_f32_16x16x32_bf16(     \
                    a_, bfr[j_], acc[mi_][j_], 0, 0, 0);                    \
        }                                                                   \
        __builtin_amdgcn_s_setprio(0);                                      \
    } while (0)

    #define WAITV(N) do {                                                   \
        asm volatile("s_waitcnt vmcnt(" #N ")" ::: "memory");               \
        __builtin_amdgcn_sched_barrier(0);                                  \
    } while (0)

    // ---- prologue: t0[9] + t1[9] in flight; drain t0, keep t1 flying ----
    GLD(0, 0);
    GLD(1, 1);
    WAITV(9);
    __builtin_amdgcn_s_barrier();

    // steady state: 17 double-iters (t = 0..33)
    #pragma unroll 1
    for (int t2 = 0; t2 < 17; ++t2) {
        const int t = 2 * t2;
        // ---- even iter t (cur=0) ----
        RD(0);                       // 17 ds_read, lgkm0, barrier (frees buf0)
        GLD(t + 2, 0);               // +9 -> 18 in flight
        MFMA36();                    // cvt fused per-mi
        WAITV(9);                    // drains t+1; t+2 stays in flight
        __builtin_amdgcn_s_barrier();
        // ---- odd iter t+1 (cur=1) ----
        RD(1);
        GLD(t + 3, 1);
        MFMA36();
        WAITV(9);
        __builtin_amdgcn_s_barrier();
    }
    // ---- t = 34 (cur=0): no staging; drain all ----
    RD(0);
    MFMA36();
    WAITV(0);
    __builtin_amdgcn_s_barrier();
    // ---- t = 35 (cur=1): compute-only ----
    RD(1);
    MFMA36();

    #undef GLD
    #undef RD
    #undef MFMA36
    #undef WAITV

    // ---- epilogue: C/D col=lane&15, row=(lane>>4)*4+reg ----
    const int orow = (lane >> 4) * 4;
    const int ocol = lane & 15;
    const int gn0 = nt * BN + wn * 144 + ocol;
    #pragma unroll
    for (int ni = 0; ni < 9; ++ni) {
        const float bv = bias[gn0 + ni * 16];
        #pragma unroll
        for (int mi = 0; mi < 4; ++mi) {
            float* po = out + (size_t)(m0 + wm * 64 + mi * 16 + orow) * NDIM
                            + gn0 + ni * 16;
            #pragma unroll
            for (int r = 0; r < 4; ++r)
                po[(size_t)r * NDIM] = acc[mi][ni][r] + bv;
        }
    }
}

extern "C" void kernel_launch(void* const* d_in, const int* in_sizes, int n_in,
                              void* d_out, int out_size, void* d_ws, size_t ws_size,
                              hipStream_t stream)
{
    const float* x  = (const float*)d_in[0];
    const float* W  = (const float*)d_in[1];
    const float* bv = (const float*)d_in[2];
    float* out = (float*)d_out;

    // ws: Bm 2.65 MB | bias 4.6 KB  (Xb eliminated)
    bf16_t* Bm   = (bf16_t*)d_ws;
    float*  bias = (float*)((char*)d_ws + (size_t)KDIM * NDIM * sizeof(bf16_t));

    build_wb<<<576, 256, 0, stream>>>(W, bv, Bm, bias);
    ind_gemm<<<512, 256, 0, stream>>>(x, Bm, bias, out);
}